// Round 7
// baseline (254.513 us; speedup 1.0000x reference)
//
#include <hip/hip_runtime.h>
#include <hip/hip_bf16.h>
#include <stdint.h>

// EdgeMessage: message[e,m] = sum_v (edges[e,:]@W[m*64+v,:] + b[m*64+v]) * vertices[e,v]
// R7: occupancy fix. Total W-frag traffic = E*64*16/M_wave is independent of
// N_wave, so split N: wave = 64 edges x 32 cols -> 3126 waves, 12.2/CU,
// 3 waves/SIMD (launch_bounds(64,3), VGPR~158<=170). Per step: 8 frag loads +
// 32 MFMA (620 SIMD-cy shadow >> L2 latency), wA/wB half-step ping-pong,
// 3 staggered waves cover each other's vmcnt gaps.
// V via Vt transpose (1 line/step). Preps fused into one launch.

typedef _Float16 f16;
typedef __attribute__((ext_vector_type(2))) _Float16 f16x2;
typedef __attribute__((ext_vector_type(8))) _Float16 f16x8;
typedef __attribute__((ext_vector_type(4))) float f32x4;

#define MSG_D 64
#define VTX_D 64
#define EDG_D 128

__device__ __forceinline__ f16x8 cvt8(float4 a, float4 d) {
  return (f16x8){(f16)a.x, (f16)a.y, (f16)a.z, (f16)a.w,
                 (f16)d.x, (f16)d.y, (f16)d.z, (f16)d.w};
}

// ---- fused prep ----
// blocks [0, nvt): V [E,64] f32 -> Vt [64,E] f16 (LDS tile transpose)
// blocks [nvt, nvt+258): W -> fragment stream Wh; b -> bias frags Bh.
//   Wh granule g = (v*16 + c)*64 + lane (c = s*4+n): f16[8] =
//     W[(n*16+ln)*64 + v][s*32 + q*8 + j], lane = q*16+ln.
//   Bh granule t2 = (s2*4 + n)*64 + lane: f16[8] = b[(n*16+ln)*64 + s2*32+q*8+j].
__global__ void prep_all(const float* __restrict__ W, const float* __restrict__ b,
                         const float* __restrict__ V,
                         f16* __restrict__ Wh, f16* __restrict__ Bh,
                         f16* __restrict__ Vt, int E, int nvt) {
  __shared__ f16 tile[64][72];
  int bx = blockIdx.x;
  if (bx < nvt) {
    int e0 = bx * 64;
    int t  = threadIdx.x;
    {
      int el = t >> 2, c4 = t & 3;        // read V[e0+el][c4*16 .. +15]
      bool ok = (e0 + el) < E;
      const float* src = V + (size_t)(ok ? e0 + el : 0) * VTX_D + c4 * 16;
      #pragma unroll
      for (int i = 0; i < 4; ++i) {
        float4 a = {0.f, 0.f, 0.f, 0.f};
        if (ok) a = *(const float4*)(src + 4 * i);
        float av[4] = {a.x, a.y, a.z, a.w};
        #pragma unroll
        for (int j = 0; j < 4; ++j) tile[c4 * 16 + i * 4 + j][el] = (f16)av[j];
      }
    }
    __syncthreads();
    int v = t & 63, c = t >> 6;           // write Vt[v][e0 + c*16 .. +15]
    int ebase = e0 + c * 16;
    union { f16 h[16]; f16x8 v8[2]; } o;
    #pragma unroll
    for (int k = 0; k < 16; ++k) o.h[k] = tile[v][c * 16 + k];
    f16* dst = Vt + (size_t)v * E + ebase;
    if (ebase + 16 <= E) {
      *(f16x8*)dst = o.v8[0];
      *(f16x8*)(dst + 8) = o.v8[1];
    } else {
      for (int k = 0; k < 16; ++k)
        if (ebase + k < E) dst[k] = o.h[k];
    }
    return;
  }
  int tid = (bx - nvt) * 256 + threadIdx.x;
  if (tid < 65536) {
    int L = tid & 63, n = (tid >> 6) & 3, s = (tid >> 8) & 3, v = tid >> 10;
    int q = L >> 4, ln = L & 15;
    const float* src = W + (size_t)((n * 16 + ln) * 64 + v) * 128 + s * 32 + q * 8;
    float4 a = *(const float4*)src, d = *(const float4*)(src + 4);
    *(f16x8*)(Wh + (size_t)tid * 8) = cvt8(a, d);
  } else if (tid < 66048) {
    int t2 = tid - 65536;
    int L = t2 & 63, n = (t2 >> 6) & 3, s2 = t2 >> 8;
    int q = L >> 4, ln = L & 15;
    const float* src = b + (n * 16 + ln) * 64 + s2 * 32 + q * 8;
    float4 a = *(const float4*)src, d = *(const float4*)(src + 4);
    *(f16x8*)(Bh + (size_t)t2 * 8) = cvt8(a, d);
  }
}

// ---- main kernel: 1 wave = 64 edges x 32 cols, no LDS, no barriers ----
template <bool USE_VT>
__global__ __launch_bounds__(64, 3) void edge_msg_flat(
    const float* __restrict__ Vtx, const float* __restrict__ Xe,
    const f16* __restrict__ Wh, const f16* __restrict__ Bh,
    const f16* __restrict__ Vt, float* __restrict__ out, int E)
{
  const int lane = threadIdx.x;
  const int q = lane >> 4, ln = lane & 15;
  const int mg = blockIdx.x >> 1;      // edge group (64 edges)
  const int nh = blockIdx.x & 1;       // n-half (32 cols)
  const int eoff = mg * 64;

  // X fragments f16 (A[m=ln][k=q*8+j] per t,s), rows clamped
  int er[4];
  f16x8 xh[4][4];
  #pragma unroll
  for (int t = 0; t < 4; ++t) {
    int e = eoff + 16 * t + ln;
    er[t] = e < E ? e : E - 1;
    const float* xr = Xe + (size_t)er[t] * EDG_D;
    #pragma unroll
    for (int s = 0; s < 4; ++s) {
      float4 a = *(const float4*)(xr + s * 32 + q * 8);
      float4 d = *(const float4*)(xr + s * 32 + q * 8 + 4);
      xh[t][s] = cvt8(a, d);
    }
  }

  f32x4 acc[4][2];
  #pragma unroll
  for (int t = 0; t < 4; ++t)
    #pragma unroll
    for (int n = 0; n < 2; ++n) acc[t][n] = (f32x4){0.f, 0.f, 0.f, 0.f};

  // frag (v, s, n) at: wp + v*8192 + s*2048 + n*512   (this wave's n-half)
  const f16* wp = Wh + (size_t)lane * 8 + (size_t)nh * 1024;

  f16x8 wA[4], wB[4];
  #pragma unroll
  for (int s = 0; s < 2; ++s)
    #pragma unroll
    for (int n = 0; n < 2; ++n)
      wA[s * 2 + n] = *(const f16x8*)(wp + s * 2048 + n * 512);

  f16 vc[4];
  #pragma unroll
  for (int t = 0; t < 4; ++t)
    vc[t] = USE_VT ? Vt[er[t]] : (f16)Vtx[(size_t)er[t] * VTX_D];

  #pragma unroll 2
  for (int v = 0; v < 64; ++v) {
    const f16* wrow  = wp + (size_t)v * 8192;
    const f16* wrowN = wp + (size_t)(v < 63 ? v + 1 : 63) * 8192;

    // load second half of step v (s=2,3) -> wB
    #pragma unroll
    for (int s = 0; s < 2; ++s)
      #pragma unroll
      for (int n = 0; n < 2; ++n)
        wB[s * 2 + n] = *(const f16x8*)(wrow + (s + 2) * 2048 + n * 512);

    // prefetch next-step V
    f16 vn[4];
    int v1 = v < 63 ? v + 1 : 63;
    #pragma unroll
    for (int t = 0; t < 4; ++t)
      vn[t] = USE_VT ? Vt[(size_t)v1 * E + er[t]]
                     : (f16)Vtx[(size_t)er[t] * VTX_D + v1];

    f16x2 hv[4];
    #pragma unroll
    for (int t = 0; t < 4; ++t) { f16 h = vc[t]; hv[t] = (f16x2){h, h}; }

    // compute s = 0,1 from wA
    #pragma unroll
    for (int s = 0; s < 2; ++s) {
      f16x8 af[4];
      #pragma unroll
      for (int t = 0; t < 4; ++t) {
        union { f16x8 v8; f16x2 h2[4]; } x, r;
        x.v8 = xh[t][s];
        r.h2[0] = hv[t] * x.h2[0];
        r.h2[1] = hv[t] * x.h2[1];
        r.h2[2] = hv[t] * x.h2[2];
        r.h2[3] = hv[t] * x.h2[3];
        af[t] = r.v8;
      }
      #pragma unroll
      for (int n = 0; n < 2; ++n)
        #pragma unroll
        for (int t = 0; t < 4; ++t)
          acc[t][n] = __builtin_amdgcn_mfma_f32_16x16x32_f16(af[t], wA[s * 2 + n], acc[t][n], 0, 0, 0);
    }

    // load first half of step v+1 -> wA
    #pragma unroll
    for (int s = 0; s < 2; ++s)
      #pragma unroll
      for (int n = 0; n < 2; ++n)
        wA[s * 2 + n] = *(const f16x8*)(wrowN + s * 2048 + n * 512);

    // compute s = 2,3 from wB
    #pragma unroll
    for (int s = 0; s < 2; ++s) {
      f16x8 af[4];
      #pragma unroll
      for (int t = 0; t < 4; ++t) {
        union { f16x8 v8; f16x2 h2[4]; } x, r;
        x.v8 = xh[t][s + 2];
        r.h2[0] = hv[t] * x.h2[0];
        r.h2[1] = hv[t] * x.h2[1];
        r.h2[2] = hv[t] * x.h2[2];
        r.h2[3] = hv[t] * x.h2[3];
        af[t] = r.v8;
      }
      #pragma unroll
      for (int n = 0; n < 2; ++n)
        #pragma unroll
        for (int t = 0; t < 4; ++t)
          acc[t][n] = __builtin_amdgcn_mfma_f32_16x16x32_f16(af[t], wB[s * 2 + n], acc[t][n], 0, 0, 0);
    }

    #pragma unroll
    for (int t = 0; t < 4; ++t) vc[t] = vn[t];
  }

  // bias: 2 K-steps, A = V-frags (original layout), B = Bh frags (our n-half)
  #pragma unroll
  for (int s2 = 0; s2 < 2; ++s2) {
    f16x8 av[4];
    #pragma unroll
    for (int t = 0; t < 4; ++t) {
      const float* vr2 = Vtx + (size_t)er[t] * VTX_D + s2 * 32 + q * 8;
      float4 a = *(const float4*)vr2, d = *(const float4*)(vr2 + 4);
      av[t] = cvt8(a, d);
    }
    #pragma unroll
    for (int n = 0; n < 2; ++n) {
      f16x8 bf = *(const f16x8*)(Bh + (size_t)((s2 * 4 + nh * 2 + n) * 64 + lane) * 8);
      #pragma unroll
      for (int t = 0; t < 4; ++t)
        acc[t][n] = __builtin_amdgcn_mfma_f32_16x16x32_f16(av[t], bf, acc[t][n], 0, 0, 0);
    }
  }

  // store: C layout col=lane&15 (m), row=q*4+r (edge) [m89-verified]
  #pragma unroll
  for (int t = 0; t < 4; ++t)
    #pragma unroll
    for (int r = 0; r < 4; ++r) {
      int e = eoff + 16 * t + 4 * q + r;
      if (e < E) {
        float* orow = out + (size_t)e * MSG_D + nh * 32 + ln;
        orow[0]  = acc[t][0][r];
        orow[16] = acc[t][1][r];
      }
    }
}

// ---- fallback (workspace too small / unexpected shape): exact fp32 ----
__global__ void edge_msg_naive(const float* __restrict__ Vtx, const float* __restrict__ Xe,
                               const float* __restrict__ W, const float* __restrict__ b,
                               float* __restrict__ out, int E) {
  __shared__ float xs[EDG_D];
  __shared__ float vs[VTX_D];
  int e = blockIdx.x;
  int m = threadIdx.x;
  for (int i = m; i < EDG_D; i += 64) xs[i] = Xe[(size_t)e * EDG_D + i];
  for (int i = m; i < VTX_D; i += 64) vs[i] = Vtx[(size_t)e * VTX_D + i];
  __syncthreads();
  float s = 0.f;
  for (int v = 0; v < VTX_D; ++v) {
    const float* wr = W + (size_t)(m * 64 + v) * EDG_D;
    float p = b[m * 64 + v];
    for (int k = 0; k < EDG_D; ++k) p += xs[k] * wr[k];
    s += p * vs[v];
  }
  out[(size_t)e * MSG_D + m] = s;
}

extern "C" void kernel_launch(void* const* d_in, const int* in_sizes, int n_in,
                              void* d_out, int out_size, void* d_ws, size_t ws_size,
                              hipStream_t stream) {
  const float* Vtx = (const float*)d_in[0];   // [E, 64]
  const float* Xe  = (const float*)d_in[1];   // [E, 128]
  const float* W   = (const float*)d_in[2];   // [4096, 128]
  const float* b   = (const float*)d_in[3];   // [4096]
  float* out = (float*)d_out;

  const int E  = in_sizes[0] / VTX_D;
  const int nW = in_sizes[2];                 // 524288
  const int nb = in_sizes[3];                 // 4096

  const size_t needW  = (size_t)(524288 + 4096) * sizeof(f16);   // ~1.01 MB
  const size_t needVt = (size_t)64 * E * sizeof(f16);            // ~12.8 MB

  if (nW != 524288 || nb != 4096 || ws_size < needW) {
    edge_msg_naive<<<E, 64, 0, stream>>>(Vtx, Xe, W, b, out, E);
    return;
  }

  f16* Wh = (f16*)d_ws;
  f16* Bh = Wh + 524288;

  int mgroups = (E + 63) / 64;
  int blocks = mgroups * 2;

  if (ws_size >= needW + needVt && (E & 7) == 0) {
    f16* Vt = Bh + 4096;
    int nvt = (E + 63) / 64;
    prep_all<<<nvt + 258, 256, 0, stream>>>(W, b, Vtx, Wh, Bh, Vt, E, nvt);
    edge_msg_flat<true><<<blocks, 64, 0, stream>>>(Vtx, Xe, Wh, Bh, Vt, out, E);
  } else {
    prep_all<<<258, 256, 0, stream>>>(W, b, Vtx, Wh, Bh, nullptr, E, 0);
    edge_msg_flat<false><<<blocks, 64, 0, stream>>>(Vtx, Xe, Wh, Bh, nullptr, out, E);
  }
}